// Round 15
// baseline (235.221 us; speedup 1.0000x reference)
//
#include <hip/hip_runtime.h>
#include <cstdint>
#include <cstddef>

#define D_MODEL 768
#define N_HEADS 12
#define HEAD_DIM 64
#define CHUNK_SZ 512
#define N_LM 32
#define BATCH 2
#define SEQ 8192
#define N_CH 16
#define SEG 256
#define TOK (BATCH*SEQ)      /* 16384 */
#define MKV_PAD 16512        /* 16384 + 64 lm/pad rows -> 129*128 */
#define QSCALE 0.18033688011112042f  /* 0.125 * log2(e): softmax done in exp2 domain */
#define DEFER_THR 12.0f              /* exp2-domain defer-max threshold (~e^8.3) */

typedef unsigned short u16;
typedef __attribute__((ext_vector_type(8))) __bf16 bf16x8;
typedef __attribute__((ext_vector_type(4))) float f32x4;

__device__ __forceinline__ u16 f2bf_rn(float f){
  union { __bf16 b; u16 u; } c; c.b = (__bf16)f; return c.u;
}

// async global->LDS, 16B per lane; LDS operand wave-uniform, HW writes lane*16B linearly.
#define GLOAD_LDS16(gp, lp) \
  __builtin_amdgcn_global_load_lds((const __attribute__((address_space(1))) void*)(gp), \
                                   (__attribute__((address_space(3))) void*)(lp), 16, 0, 0)

// bijective XCD-chunked remap (m204)
__device__ __forceinline__ int xcd_remap(int bid, int nwg){
  int q = nwg >> 3, r = nwg & 7;
  int xcd = bid & 7, j = bid >> 3;
  return (xcd < r ? xcd*(q+1) : r*(q+1) + (xcd-r)*q) + j;
}

// ---------------- all 4 weight converts in one launch ----------------
__global__ __launch_bounds__(256) void cvt4_kernel(
    const float* __restrict__ w0, const float* __restrict__ w1,
    const float* __restrict__ w2, const float* __restrict__ w3,
    u16* __restrict__ o0, u16* __restrict__ o1, u16* __restrict__ o2, u16* __restrict__ o3)
{
  const int n4 = D_MODEL*D_MODEL/4;
  int i = blockIdx.x*256 + threadIdx.x;
  int sel = i / n4, j = i - sel*n4;
  const float* s = sel==0 ? w0 : sel==1 ? w1 : sel==2 ? w2 : w3;
  u16* o = sel==0 ? o0 : sel==1 ? o1 : sel==2 ? o2 : o3;
  float4 v = reinterpret_cast<const float4*>(s)[j];
  ushort4 p; p.x=f2bf_rn(v.x); p.y=f2bf_rn(v.y); p.z=f2bf_rn(v.z); p.w=f2bf_rn(v.w);
  reinterpret_cast<ushort4*>(o)[j] = p;
}

// ---- xcat rows [0,TOK) = bf16(x); rows [TOK,MKV_PAD) = 0 (landmarks overwritten later)
__global__ void build_xcat_kernel(const float* __restrict__ x, u16* __restrict__ xcat){
  const int total4 = MKV_PAD * D_MODEL / 4;
  const int x4 = TOK * D_MODEL / 4;
  int stride = gridDim.x * blockDim.x;
  for (int i = blockIdx.x*blockDim.x + threadIdx.x; i < total4; i += stride){
    ushort4 o;
    if (i < x4){
      float4 v = reinterpret_cast<const float4*>(x)[i];
      o.x = f2bf_rn(v.x); o.y = f2bf_rn(v.y); o.z = f2bf_rn(v.z); o.w = f2bf_rn(v.w);
    } else { o.x = 0; o.y = 0; o.z = 0; o.w = 0; }
    reinterpret_cast<ushort4*>(xcat)[i] = o;
  }
}

// ---------------- landmark mean-pool, two-stage ----------------
__global__ __launch_bounds__(256) void lm_part_kernel(const float* __restrict__ x, float* __restrict__ lmp){
  int seg = blockIdx.x >> 3, sub = blockIdx.x & 7;
  int b = seg >> 5, l = seg & 31;
  const float* base = x + ((size_t)b*SEQ + (size_t)l*SEG + (size_t)sub*32) * D_MODEL;
  int d = threadIdx.x;
  float a0=0.f, a1=0.f, a2=0.f;
  for (int tt=0; tt<32; ++tt){
    const float* row = base + (size_t)tt*D_MODEL;
    a0 += row[d]; a1 += row[d+256]; a2 += row[d+512];
  }
  float* orow = lmp + (size_t)blockIdx.x * D_MODEL;
  orow[d] = a0; orow[d+256] = a1; orow[d+512] = a2;
}
__global__ __launch_bounds__(256) void lm_final_kernel(const float* __restrict__ lmp, u16* __restrict__ xcat){
  int seg = blockIdx.x;
  int d = threadIdx.x;
  float a0=0.f, a1=0.f, a2=0.f;
  #pragma unroll
  for (int i=0;i<8;i++){
    const float* p = lmp + ((size_t)seg*8 + i)*D_MODEL;
    a0 += p[d]; a1 += p[d+256]; a2 += p[d+512];
  }
  u16* orow = xcat + ((size_t)TOK + seg)*D_MODEL;
  const float inv = 1.f/(float)SEG;
  orow[d] = f2bf_rn(a0*inv); orow[d+256] = f2bf_rn(a1*inv); orow[d+512] = f2bf_rn(a2*inv);
}

// ---------------- GEMM main loop (R11: dbuf + both-sides swizzle + counted vmcnt) ----------------
#define GEMM_PROLOG                                                                \
  const int t = threadIdx.x;                                                       \
  const int lane = t & 63, wid = t >> 6;                                           \
  const int wr = wid >> 1, wc = wid & 1;                                           \
  const int lr = lane & 15, lg = lane >> 4;

#define GEMM_MAINLOOP(Aptr, Bptr)                                                  \
  __shared__ u16 As[2*128*64];                                                     \
  __shared__ u16 Bs[2*128*64];                                                     \
  const int srow = lane >> 3;                                                      \
  const int scolx = (((lane & 7) ^ (lane >> 3)) << 3);  /* inverse-swizzled src */ \
  const u16* ga = (Aptr) + (row0 + srow)*(size_t)D_MODEL + scolx;                  \
  const u16* gb = (Bptr) + ((size_t)col0 + srow)*(size_t)D_MODEL + scolx;          \
  f32x4 acc[4][4];                                                                 \
  _Pragma("unroll") for (int m=0;m<4;m++)                                          \
    _Pragma("unroll") for (int n=0;n<4;n++) acc[m][n] = f32x4{0.f,0.f,0.f,0.f};    \
  {                                                                                \
    _Pragma("unroll") for (int i=0;i<4;i++){                                       \
      int chunk = wid*4 + i;                                                       \
      GLOAD_LDS16(ga + (size_t)chunk*8*D_MODEL, As + chunk*512);                   \
      GLOAD_LDS16(gb + (size_t)chunk*8*D_MODEL, Bs + chunk*512);                   \
    }                                                                              \
  }                                                                                \
  int cur = 0;                                                                     \
  const int rsw = (lr & 7) << 3;                                                   \
  for (int ts = 0; ts < D_MODEL/64; ++ts){                                         \
    __builtin_amdgcn_s_barrier();   /* A: all waves done reading buf cur^1 */      \
    if (ts < D_MODEL/64 - 1){                                                      \
      int nb = (cur ^ 1) * 8192;                                                   \
      _Pragma("unroll") for (int i=0;i<4;i++){                                     \
        int chunk = wid*4 + i;                                                     \
        GLOAD_LDS16(ga + (size_t)chunk*8*D_MODEL + (ts+1)*64, As + nb + chunk*512);\
        GLOAD_LDS16(gb + (size_t)chunk*8*D_MODEL + (ts+1)*64, Bs + nb + chunk*512);\
      }                                                                            \
      asm volatile("s_waitcnt vmcnt(8)" ::: "memory");  /* buf[cur] landed */      \
    } else {                                                                       \
      asm volatile("s_waitcnt vmcnt(0)" ::: "memory");                             \
    }                                                                              \
    __builtin_amdgcn_s_barrier();   /* B: everyone's buf[cur] visible */           \
    __builtin_amdgcn_sched_barrier(0);                                             \
    int cb = cur * 8192;                                                           \
    _Pragma("unroll") for (int kk=0;kk<2;kk++){                                    \
      bf16x8 af[4], bv[4];                                                         \
      _Pragma("unroll") for (int m=0;m<4;m++)                                      \
        af[m] = *reinterpret_cast<const bf16x8*>(                                  \
            &As[cb + (wr*64 + m*16 + lr)*64 + ((kk*32 + lg*8) ^ rsw)]);            \
      _Pragma("unroll") for (int n=0;n<4;n++)                                      \
        bv[n] = *reinterpret_cast<const bf16x8*>(                                  \
            &Bs[cb + (wc*64 + n*16 + lr)*64 + ((kk*32 + lg*8) ^ rsw)]);            \
      _Pragma("unroll") for (int m=0;m<4;m++)                                      \
        _Pragma("unroll") for (int n=0;n<4;n++)                                    \
          acc[m][n] = __builtin_amdgcn_mfma_f32_16x16x32_bf16(af[m], bv[n], acc[m][n], 0, 0, 0); \
    }                                                                              \
    cur ^= 1;                                                                      \
  }

// generic: C[M][N] = A * Bt^T + bias, *scale. 1-D grid, XCD-chunked. LDS-repack epilogue.
template<int OUT_F32, int BIAS_ROW, int ROWFAST, int NFAST>
__global__ __launch_bounds__(256) void gemm_bt_kernel(
    const u16* __restrict__ A, const u16* __restrict__ Bt,
    const float* __restrict__ bias, void* __restrict__ Cout, int ldc, float scale)
{
  int g = xcd_remap(blockIdx.x, gridDim.x);
  int rowt, colt;
  if (ROWFAST){ rowt = g % NFAST; colt = g / NFAST; }
  else        { colt = g % NFAST; rowt = g / NFAST; }
  const size_t row0 = (size_t)rowt * 128;
  const int col0 = colt * 128;
  GEMM_PROLOG
  GEMM_MAINLOOP(A, Bt)

  __syncthreads();   // main-loop LDS reads complete before As/Bs reuse
  if (OUT_F32){
    float* Fw = reinterpret_cast<float*>(wid < 2 ? As : Bs) + (wid & 1) * 4096;  // 64x64 f32
    #pragma unroll
    for (int m=0;m<4;m++){
      #pragma unroll
      for (int n=0;n<4;n++){
        const int col = col0 + wc*64 + n*16 + lr;
        const float bcol = BIAS_ROW ? 0.f : bias[col];
        #pragma unroll
        for (int e=0;e<4;e++){
          size_t row = row0 + wr*64 + m*16 + lg*4 + e;
          float b = BIAS_ROW ? bias[row] : bcol;
          Fw[(m*16 + lg*4 + e)*64 + n*16 + lr] = (acc[m][n][e] + b) * scale;
        }
      }
    }
    __syncthreads();
    float* fo = reinterpret_cast<float*>(Cout);
    #pragma unroll
    for (int i=0;i<16;i++){
      int rr = i*4 + (lane >> 4), cc = (lane & 15) * 4;
      float4 v = *reinterpret_cast<const float4*>(&Fw[rr*64 + cc]);
      *reinterpret_cast<float4*>(&fo[(row0 + wr*64 + rr)*(size_t)ldc + col0 + wc*64 + cc]) = v;
    }
  } else {
    u16* Cw = (wid < 2 ? As : Bs) + (wid & 1) * 4608;  // 64x72 u16 (pad 72)
    #pragma unroll
    for (int m=0;m<4;m++){
      #pragma unroll
      for (int n=0;n<4;n++){
        const int col = col0 + wc*64 + n*16 + lr;
        const float bcol = BIAS_ROW ? 0.f : bias[col];
        #pragma unroll
        for (int e=0;e<4;e++){
          size_t row = row0 + wr*64 + m*16 + lg*4 + e;
          float b = BIAS_ROW ? bias[row] : bcol;
          Cw[(m*16 + lg*4 + e)*72 + n*16 + lr] = f2bf_rn((acc[m][n][e] + b) * scale);
        }
      }
    }
    __syncthreads();
    u16* uo = reinterpret_cast<u16*>(Cout);
    #pragma unroll
    for (int i=0;i<8;i++){
      int rr = i*8 + (lane >> 3), cc = (lane & 7) * 8;
      bf16x8 v = *reinterpret_cast<const bf16x8*>(&Cw[rr*72 + cc]);
      *reinterpret_cast<bf16x8*>(&uo[(row0 + wr*64 + rr)*(size_t)ldc + col0 + wc*64 + cc]) = v;
    }
  }
}

// fused Q+K: Bt = wq||wk concat [1536][768]; 12 col tiles fastest. LDS-repack epilogue.
__global__ __launch_bounds__(256) void gemm_qk_kernel(
    const u16* __restrict__ A, const u16* __restrict__ Wqk,
    const float* __restrict__ bq, const float* __restrict__ bk,
    u16* __restrict__ Qb, u16* __restrict__ Kb)
{
  int g = xcd_remap(blockIdx.x, gridDim.x);
  int colt = g % 12, rowt = g / 12;
  const size_t row0 = (size_t)rowt * 128;
  const int col0 = colt * 128;
  GEMM_PROLOG
  GEMM_MAINLOOP(A, Wqk)

  const bool isk = col0 >= 768;
  const float scale = isk ? 1.f : QSCALE;
  u16* dst = isk ? Kb : Qb;
  const int ocol0 = isk ? col0 - 768 : col0;

  __syncthreads();
  u16* Cw = (wid < 2 ? As : Bs) + (wid & 1) * 4608;  // 64x72 u16
  #pragma unroll
  for (int m=0;m<4;m++){
    #pragma unroll
    for (int n=0;n<4;n++){
      const int ocol = ocol0 + wc*64 + n*16 + lr;
      const float b = isk ? bk[ocol] : bq[ocol];
      #pragma unroll
      for (int e=0;e<4;e++)
        Cw[(m*16 + lg*4 + e)*72 + n*16 + lr] = f2bf_rn((acc[m][n][e] + b) * scale);
    }
  }
  __syncthreads();
  #pragma unroll
  for (int i=0;i<8;i++){
    int rr = i*8 + (lane >> 3), cc = (lane & 7) * 8;
    size_t grow = row0 + wr*64 + rr;
    if (isk || grow < TOK){
      bf16x8 v = *reinterpret_cast<const bf16x8*>(&Cw[rr*72 + cc]);
      *reinterpret_cast<bf16x8*>(&dst[grow*D_MODEL + ocol0 + wc*64 + cc]) = v;
    }
  }
}

// ---------------- attention compute for one staged KV tile ----------------
// Pw has 32 rows per wave: r's P fragment lives in rows [r*16, r*16+16) — no false
// LDS dependency between r=0's PV read and r=1's P write. Softmax for BOTH r runs
// first (two independent VALU chains interleave), then both PV MFMA blocks.
template<int NK>
__device__ __forceinline__ void attn_compute(
    int lr, int lg,
    const u16 (* __restrict__ Ks)[72], const u16 (* __restrict__ Vs)[72],
    u16 (* __restrict__ Pw)[68],
    const bf16x8 (&qf)[2][2], float (&m_run)[2], float (&l_run)[2], f32x4 (&of)[2][4])
{
  constexpr int NCF = NK/16;
  constexpr int NKT = NK/32;

  f32x4 s2[2][NCF];
  #pragma unroll
  for (int c=0;c<NCF;c++){
    bf16x8 kf0 = *reinterpret_cast<const bf16x8*>(&Ks[c*16 + lr][lg*8]);
    bf16x8 kf1 = *reinterpret_cast<const bf16x8*>(&Ks[c*16 + lr][32 + lg*8]);
    #pragma unroll
    for (int r=0;r<2;r++){
      f32x4 s = f32x4{0.f,0.f,0.f,0.f};
      s = __builtin_amdgcn_mfma_f32_16x16x32_bf16(kf0, qf[r][0], s, 0,0,0);
      s = __builtin_amdgcn_mfma_f32_16x16x32_bf16(kf1, qf[r][1], s, 0,0,0);
      s2[r][c] = s;
    }
  }

  bf16x8 vf[NKT][4];
  #pragma unroll
  for (int kt=0;kt<NKT;kt++)
    #pragma unroll
    for (int c=0;c<4;c++)
      vf[kt][c] = *reinterpret_cast<const bf16x8*>(&Vs[c*16 + lr][kt*32 + lg*8]);

  // ---- softmax for both r (independent chains; compiler interleaves) ----
  #pragma unroll
  for (int r=0;r<2;r++){
    float tm = s2[r][0][0];
    #pragma unroll
    for (int c=0;c<NCF;c++)
      #pragma unroll
      for (int e=0;e<4;e++) tm = fmaxf(tm, s2[r][c][e]);
    tm = fmaxf(tm, __shfl_xor(tm, 16, 64));
    tm = fmaxf(tm, __shfl_xor(tm, 32, 64));
    if (!__all(tm - m_run[r] <= DEFER_THR)){
      float mnew = fmaxf(m_run[r], tm);
      float al = exp2f(m_run[r] - mnew);
      m_run[r] = mnew;
      l_run[r] *= al;
      #pragma unroll
      for (int c=0;c<4;c++)
        #pragma unroll
        for (int e=0;e<4;e++) of[r][c][e] *= al;
    }
    float ts = 0.f;
    #pragma unroll
    for (int c=0;c<NCF;c++)
      #pragma unroll
      for (int e=0;e<4;e++){
        float p = exp2f(s2[r][c][e] - m_run[r]);
        s2[r][c][e] = p;
        ts += p;
      }
    ts += __shfl_xor(ts, 16, 64);
    ts += __shfl_xor(ts, 32, 64);
    l_run[r] += ts;

    #pragma unroll
    for (int c=0;c<NCF;c++){
      ushort4 pk;
      pk.x = f2bf_rn(s2[r][c][0]); pk.y = f2bf_rn(s2[r][c][1]);
      pk.z = f2bf_rn(s2[r][c][2]); pk.w = f2bf_rn(s2[r][c][3]);
      *reinterpret_cast<ushort4*>(&Pw[r*16 + lr][c*16 + lg*4]) = pk;
    }
  }

  // ---- PV for both r (back-to-back MFMA; P writes long since retired) ----
  #pragma unroll
  for (int r=0;r<2;r++){
    #pragma unroll
    for (int kt=0;kt<NKT;kt++){
      bf16x8 pf = *reinterpret_cast<const bf16x8*>(&Pw[r*16 + lr][kt*32 + lg*8]);
      #pragma unroll
      for (int c=0;c<4;c++)
        of[r][c] = __builtin_amdgcn_mfma_f32_16x16x32_bf16(vf[kt][c], pf, of[r][c], 0,0,0);
    }
  }
}

// ---------------- attention: 512 thr / 8 waves, 256 q-rows per block ----------------
__global__ __launch_bounds__(512) void attn_kernel(
    const u16* __restrict__ Qb, const u16* __restrict__ Kb,
    const u16* __restrict__ Vt, u16* __restrict__ AO)
{
  __shared__ u16 Ks[64][72];
  __shared__ u16 Vs[64][72];
  __shared__ u16 PwAll[8][32][68];

  const int t = threadIdx.x;
  const int lane = t & 63, w = t >> 6;          // 8 waves
  const int lr = lane & 15, lg = lane >> 4;
  const int qh = blockIdx.x;                    // 0..1: 256-row half of the chunk
  const int h  = blockIdx.y;
  const int b  = blockIdx.z >> 4, ch = blockIdx.z & 15;
  const size_t tok0 = (size_t)b*SEQ + (size_t)ch*CHUNK_SZ + (size_t)qh*256;
  const size_t bch0 = (size_t)b*SEQ + (size_t)ch*CHUNK_SZ;
  u16 (* __restrict__ Pw)[68] = PwAll[w];

  bf16x8 qf[2][2];
  #pragma unroll
  for (int r=0;r<2;r++)
    #pragma unroll
    for (int kk=0;kk<2;kk++)
      qf[r][kk] = *reinterpret_cast<const bf16x8*>(
          &Qb[(tok0 + w*32 + r*16 + lr)*D_MODEL + (size_t)h*HEAD_DIM + kk*32 + lg*8]);

  float m_run[2] = {-INFINITY, -INFINITY};
  float l_run[2] = {0.f, 0.f};
  f32x4 of[2][4];
  #pragma unroll
  for (int r=0;r<2;r++)
    #pragma unroll
    for (int c=0;c<4;c++) of[r][c] = f32x4{0.f,0.f,0.f,0.f};

  // ---- landmark tile (32 keys), staged by waves 0-3 ----
  if (t < 256){
    const size_t lmrow0 = (size_t)TOK + (size_t)b*N_LM;
    int key = t >> 3, dc = (t & 7) << 3;
    *reinterpret_cast<bf16x8*>(&Ks[key][dc]) = *reinterpret_cast<const bf16x8*>(
        &Kb[(lmrow0 + key)*D_MODEL + (size_t)h*HEAD_DIM + dc]);
    int d = t >> 2, kc = (t & 3) << 3;
    *reinterpret_cast<bf16x8*>(&Vs[d][kc]) = *reinterpret_cast<const bf16x8*>(
        &Vt[((size_t)h*HEAD_DIM + d)*MKV_PAD + lmrow0 + kc]);
  }
  __syncthreads();
  attn_compute<32>(lr, lg, Ks, Vs, Pw, qf, m_run, l_run, of);

  // ---- 8 local tiles of 64 keys, reg-prefetched; 1 K + 1 V load per thread per tile ----
  bf16x8 kreg, vreg;
  const int key0 = t >> 3, dc0 = (t & 7) << 3;   // 512 thr: keys 0..63 x 8 col-chunks
  const int d0 = t >> 3, kc0 = (t & 7) << 3;
  {
    size_t col0 = bch0;
    kreg = *reinterpret_cast<const bf16x8*>(&Kb[(col0 + key0)*D_MODEL + (size_t)h*HEAD_DIM + dc0]);
    vreg = *reinterpret_cast<const bf16x8*>(&Vt[((size_t)h*HEAD_DIM + d0)*MKV_PAD + col0 + kc0]);
  }
  for (int tl = 0; tl < 8; ++tl){
    __syncthreads();
    *reinterpret_cast<bf16x8*>(&Ks[key0][dc0]) = kreg;
    *reinterpret_cast<bf16x8*>(&Vs[d0][kc0])   = vreg;
    __syncthreads();
    if (tl < 7){
      size_t col0 = bch0 + (size_t)(tl+1)*64;
      kreg = *reinterpret_cast<const bf16x8*>(&Kb[(col0 + key0)*D_MODEL + (size_t)h*HEAD_DIM + dc0]);
      vreg = *reinterpret_cast<const bf16x8*>(&Vt[((size_t)h*HEAD_DIM + d0)*MKV_PAD + col0 + kc0]);
    }
    attn_compute<64>(lr, lg, Ks, Vs, Pw, qf, m_run, l_run, of);
  }

  // ---- epilogue ----
  #pragma unroll
  for (int r=0;r<2;r++){
    float inv = 1.f / l_run[r];
    size_t row = (tok0 + w*32 + r*16 + lr)*D_MODEL + (size_t)h*HEAD_DIM;
    #pragma unroll
    for (int c=0;c<4;c++){
      ushort4 pk;
      pk.x = f2bf_rn(of[r][c][0]*inv); pk.y = f2bf_rn(of[r][c][1]*inv);
      pk.z = f2bf_rn(of[r][c][2]*inv); pk.w = f2bf_rn(of[r][c][3]*inv);
      *reinterpret_cast<ushort4*>(&AO[row + c*16 + lg*4]) = pk;
    }
  }
}

// ---------------- launch ----------------
extern "C" void kernel_launch(void* const* d_in, const int* in_sizes, int n_in,
                              void* d_out, int out_size, void* d_ws, size_t ws_size,
                              hipStream_t stream) {
  const float* x  = (const float*)d_in[0];
  const float* Wq = (const float*)d_in[1];
  const float* bq = (const float*)d_in[2];
  const float* Wk = (const float*)d_in[3];
  const float* bk = (const float*)d_in[4];
  const float* Wv = (const float*)d_in[5];
  const float* bv = (const float*)d_in[6];
  const float* Wo = (const float*)d_in[7];
  const float* bo = (const float*)d_in[8];
  float* out = (float*)d_out;

  // workspace layout (bytes)
  const size_t XCAT_OFF = 0;
  const size_t Q_OFF    = 25362432;
  const size_t K_OFF    = 50528256;
  const size_t VT_OFF   = 75890688;
  const size_t AO_OFF   = 101253120;
  const size_t WQ_OFF   = 126418944;
  const size_t WK_OFF   = 127598592;
  const size_t WV_OFF   = 128778240;
  const size_t WO_OFF   = 129957888;
  const size_t TOTAL    = 131137536;
  if (ws_size < TOTAL) return;

  char* ws = (char*)d_ws;
  u16* xcat = (u16*)(ws + XCAT_OFF);
  u16* Qb   = (u16*)(ws + Q_OFF);
  u16* Kb   = (u16*)(ws + K_OFF);
  u16* Vt   = (u16*)(ws + VT_OFF);
  u16* AO   = (u16*)(ws + AO_OFF);
  float* lmp = (float*)(ws + AO_OFF);
  u16* wqkb = (u16*)(ws + WQ_OFF);
  u16* wkb  = (u16*)(ws + WK_OFF);
  u16* wvb  = (u16*)(ws + WV_OFF);
  u16* wob  = (u16*)(ws + WO_OFF);

  dim3 blk(256);
  cvt4_kernel<<<dim3(2304), blk, 0, stream>>>(Wq, Wk, Wv, Wo, wqkb, wkb, wvb, wob);
  build_xcat_kernel<<<dim3(4096), blk, 0, stream>>>(x, xcat);
  lm_part_kernel<<<dim3(512), blk, 0, stream>>>(x, lmp);
  lm_final_kernel<<<dim3(64), blk, 0, stream>>>(lmp, xcat);

  // fused Q+K: 129 row tiles x 12 col tiles, col-fastest within XCD chunk
  gemm_qk_kernel<<<dim3(1548), blk, 0, stream>>>(xcat, wqkb, bq, bk, Qb, Kb);
  // V^T = Wv * xcat^T: 6 row tiles (wv) x 129 col tiles (tokens), row-fastest
  gemm_bt_kernel<0,1,1,6><<<dim3(774), blk, 0, stream>>>(wvb, xcat, bv, (void*)Vt, MKV_PAD, 1.f);

  attn_kernel<<<dim3(2, 12, 32), dim3(512), 0, stream>>>(Qb, Kb, Vt, AO);

  // out = AO * wo^T + bo: 128 row tiles x 6 col tiles, col-fastest
  gemm_bt_kernel<1,0,0,6><<<dim3(768), blk, 0, stream>>>(AO, wob, bo, (void*)out, D_MODEL, 1.f);
}

// Round 16
// 223.476 us; speedup vs baseline: 1.0526x; 1.0526x over previous
//
#include <hip/hip_runtime.h>
#include <cstdint>
#include <cstddef>

#define D_MODEL 768
#define N_HEADS 12
#define HEAD_DIM 64
#define CHUNK_SZ 512
#define N_LM 32
#define BATCH 2
#define SEQ 8192
#define N_CH 16
#define SEG 256
#define TOK (BATCH*SEQ)      /* 16384 */
#define MKV_PAD 16512        /* 16384 + 64 lm/pad rows -> 129*128 */
#define QSCALE 0.18033688011112042f  /* 0.125 * log2(e): softmax done in exp2 domain */
#define DEFER_THR 12.0f              /* exp2-domain defer-max threshold (~e^8.3) */

typedef unsigned short u16;
typedef __attribute__((ext_vector_type(8))) __bf16 bf16x8;
typedef __attribute__((ext_vector_type(4))) float f32x4;

__device__ __forceinline__ u16 f2bf_rn(float f){
  union { __bf16 b; u16 u; } c; c.b = (__bf16)f; return c.u;
}
__device__ __forceinline__ float bf2f(u16 u){
  union { unsigned i; float f; } c; c.i = ((unsigned)u) << 16; return c.f;
}

// async global->LDS, 16B per lane; LDS operand wave-uniform, HW writes lane*16B linearly.
#define GLOAD_LDS16(gp, lp) \
  __builtin_amdgcn_global_load_lds((const __attribute__((address_space(1))) void*)(gp), \
                                   (__attribute__((address_space(3))) void*)(lp), 16, 0, 0)

// bijective XCD-chunked remap (m204)
__device__ __forceinline__ int xcd_remap(int bid, int nwg){
  int q = nwg >> 3, r = nwg & 7;
  int xcd = bid & 7, j = bid >> 3;
  return (xcd < r ? xcd*(q+1) : r*(q+1) + (xcd-r)*q) + j;
}

// ---------------- all 4 weight converts in one launch ----------------
__global__ __launch_bounds__(256) void cvt4_kernel(
    const float* __restrict__ w0, const float* __restrict__ w1,
    const float* __restrict__ w2, const float* __restrict__ w3,
    u16* __restrict__ o0, u16* __restrict__ o1, u16* __restrict__ o2, u16* __restrict__ o3)
{
  const int n4 = D_MODEL*D_MODEL/4;
  int i = blockIdx.x*256 + threadIdx.x;
  int sel = i / n4, j = i - sel*n4;
  const float* s = sel==0 ? w0 : sel==1 ? w1 : sel==2 ? w2 : w3;
  u16* o = sel==0 ? o0 : sel==1 ? o1 : sel==2 ? o2 : o3;
  float4 v = reinterpret_cast<const float4*>(s)[j];
  ushort4 p; p.x=f2bf_rn(v.x); p.y=f2bf_rn(v.y); p.z=f2bf_rn(v.z); p.w=f2bf_rn(v.w);
  reinterpret_cast<ushort4*>(o)[j] = p;
}

// ---- xcat rows [0,TOK) = bf16(x); rows [TOK,MKV_PAD) = 0 (landmarks overwritten later)
__global__ void build_xcat_kernel(const float* __restrict__ x, u16* __restrict__ xcat){
  const int total4 = MKV_PAD * D_MODEL / 4;
  const int x4 = TOK * D_MODEL / 4;
  int stride = gridDim.x * blockDim.x;
  for (int i = blockIdx.x*blockDim.x + threadIdx.x; i < total4; i += stride){
    ushort4 o;
    if (i < x4){
      float4 v = reinterpret_cast<const float4*>(x)[i];
      o.x = f2bf_rn(v.x); o.y = f2bf_rn(v.y); o.z = f2bf_rn(v.z); o.w = f2bf_rn(v.w);
    } else { o.x = 0; o.y = 0; o.z = 0; o.w = 0; }
    reinterpret_cast<ushort4*>(xcat)[i] = o;
  }
}

// ---------------- landmark mean-pool, two-stage (stage 1 reads xcat bf16: 25MB not 50MB) ----------------
__global__ __launch_bounds__(256) void lm_part_kernel(const u16* __restrict__ xcat, float* __restrict__ lmp){
  const u16* base = xcat + (size_t)blockIdx.x*32*D_MODEL;
  int d = threadIdx.x;
  float a0=0.f, a1=0.f, a2=0.f;
  for (int tt=0; tt<32; ++tt){
    const u16* row = base + (size_t)tt*D_MODEL;
    a0 += bf2f(row[d]); a1 += bf2f(row[d+256]); a2 += bf2f(row[d+512]);
  }
  float* orow = lmp + (size_t)blockIdx.x * D_MODEL;
  orow[d] = a0; orow[d+256] = a1; orow[d+512] = a2;
}
__global__ __launch_bounds__(256) void lm_final_kernel(const float* __restrict__ lmp, u16* __restrict__ xcat){
  int seg = blockIdx.x;
  int d = threadIdx.x;
  float a0=0.f, a1=0.f, a2=0.f;
  #pragma unroll
  for (int i=0;i<8;i++){
    const float* p = lmp + ((size_t)seg*8 + i)*D_MODEL;
    a0 += p[d]; a1 += p[d+256]; a2 += p[d+512];
  }
  u16* orow = xcat + ((size_t)TOK + seg)*D_MODEL;
  const float inv = 1.f/(float)SEG;
  orow[d] = f2bf_rn(a0*inv); orow[d+256] = f2bf_rn(a1*inv); orow[d+512] = f2bf_rn(a2*inv);
}

// ---------------- GEMM main loop (R11: dbuf + both-sides swizzle + counted vmcnt) ----------------
#define GEMM_PROLOG                                                                \
  const int t = threadIdx.x;                                                       \
  const int lane = t & 63, wid = t >> 6;                                           \
  const int wr = wid >> 1, wc = wid & 1;                                           \
  const int lr = lane & 15, lg = lane >> 4;

#define GEMM_MAINLOOP(Aptr, Bptr)                                                  \
  __shared__ u16 As[2*128*64];                                                     \
  __shared__ u16 Bs[2*128*64];                                                     \
  const int srow = lane >> 3;                                                      \
  const int scolx = (((lane & 7) ^ (lane >> 3)) << 3);  /* inverse-swizzled src */ \
  const u16* ga = (Aptr) + (row0 + srow)*(size_t)D_MODEL + scolx;                  \
  const u16* gb = (Bptr) + ((size_t)col0 + srow)*(size_t)D_MODEL + scolx;          \
  f32x4 acc[4][4];                                                                 \
  _Pragma("unroll") for (int m=0;m<4;m++)                                          \
    _Pragma("unroll") for (int n=0;n<4;n++) acc[m][n] = f32x4{0.f,0.f,0.f,0.f};    \
  {                                                                                \
    _Pragma("unroll") for (int i=0;i<4;i++){                                       \
      int chunk = wid*4 + i;                                                       \
      GLOAD_LDS16(ga + (size_t)chunk*8*D_MODEL, As + chunk*512);                   \
      GLOAD_LDS16(gb + (size_t)chunk*8*D_MODEL, Bs + chunk*512);                   \
    }                                                                              \
  }                                                                                \
  int cur = 0;                                                                     \
  const int rsw = (lr & 7) << 3;                                                   \
  for (int ts = 0; ts < D_MODEL/64; ++ts){                                         \
    __builtin_amdgcn_s_barrier();   /* A: all waves done reading buf cur^1 */      \
    if (ts < D_MODEL/64 - 1){                                                      \
      int nb = (cur ^ 1) * 8192;                                                   \
      _Pragma("unroll") for (int i=0;i<4;i++){                                     \
        int chunk = wid*4 + i;                                                     \
        GLOAD_LDS16(ga + (size_t)chunk*8*D_MODEL + (ts+1)*64, As + nb + chunk*512);\
        GLOAD_LDS16(gb + (size_t)chunk*8*D_MODEL + (ts+1)*64, Bs + nb + chunk*512);\
      }                                                                            \
      asm volatile("s_waitcnt vmcnt(8)" ::: "memory");  /* buf[cur] landed */      \
    } else {                                                                       \
      asm volatile("s_waitcnt vmcnt(0)" ::: "memory");                             \
    }                                                                              \
    __builtin_amdgcn_s_barrier();   /* B: everyone's buf[cur] visible */           \
    __builtin_amdgcn_sched_barrier(0);                                             \
    int cb = cur * 8192;                                                           \
    _Pragma("unroll") for (int kk=0;kk<2;kk++){                                    \
      bf16x8 af[4], bv[4];                                                         \
      _Pragma("unroll") for (int m=0;m<4;m++)                                      \
        af[m] = *reinterpret_cast<const bf16x8*>(                                  \
            &As[cb + (wr*64 + m*16 + lr)*64 + ((kk*32 + lg*8) ^ rsw)]);            \
      _Pragma("unroll") for (int n=0;n<4;n++)                                      \
        bv[n] = *reinterpret_cast<const bf16x8*>(                                  \
            &Bs[cb + (wc*64 + n*16 + lr)*64 + ((kk*32 + lg*8) ^ rsw)]);            \
      _Pragma("unroll") for (int m=0;m<4;m++)                                      \
        _Pragma("unroll") for (int n=0;n<4;n++)                                    \
          acc[m][n] = __builtin_amdgcn_mfma_f32_16x16x32_bf16(af[m], bv[n], acc[m][n], 0, 0, 0); \
    }                                                                              \
    cur ^= 1;                                                                      \
  }

// generic: C[M][N] = A * Bt^T + bias, *scale. 1-D grid, XCD-chunked. LDS-repack epilogue.
template<int OUT_F32, int BIAS_ROW, int ROWFAST, int NFAST>
__global__ __launch_bounds__(256) void gemm_bt_kernel(
    const u16* __restrict__ A, const u16* __restrict__ Bt,
    const float* __restrict__ bias, void* __restrict__ Cout, int ldc, float scale)
{
  int g = xcd_remap(blockIdx.x, gridDim.x);
  int rowt, colt;
  if (ROWFAST){ rowt = g % NFAST; colt = g / NFAST; }
  else        { colt = g % NFAST; rowt = g / NFAST; }
  const size_t row0 = (size_t)rowt * 128;
  const int col0 = colt * 128;
  GEMM_PROLOG
  GEMM_MAINLOOP(A, Bt)

  __syncthreads();   // main-loop LDS reads complete before As/Bs reuse
  if (OUT_F32){
    float* Fw = reinterpret_cast<float*>(wid < 2 ? As : Bs) + (wid & 1) * 4096;  // 64x64 f32
    #pragma unroll
    for (int m=0;m<4;m++){
      #pragma unroll
      for (int n=0;n<4;n++){
        const int col = col0 + wc*64 + n*16 + lr;
        const float bcol = BIAS_ROW ? 0.f : bias[col];
        #pragma unroll
        for (int e=0;e<4;e++){
          size_t row = row0 + wr*64 + m*16 + lg*4 + e;
          float b = BIAS_ROW ? bias[row] : bcol;
          Fw[(m*16 + lg*4 + e)*64 + n*16 + lr] = (acc[m][n][e] + b) * scale;
        }
      }
    }
    __syncthreads();
    float* fo = reinterpret_cast<float*>(Cout);
    #pragma unroll
    for (int i=0;i<16;i++){
      int rr = i*4 + (lane >> 4), cc = (lane & 15) * 4;
      float4 v = *reinterpret_cast<const float4*>(&Fw[rr*64 + cc]);
      *reinterpret_cast<float4*>(&fo[(row0 + wr*64 + rr)*(size_t)ldc + col0 + wc*64 + cc]) = v;
    }
  } else {
    u16* Cw = (wid < 2 ? As : Bs) + (wid & 1) * 4608;  // 64x72 u16 (pad 72)
    #pragma unroll
    for (int m=0;m<4;m++){
      #pragma unroll
      for (int n=0;n<4;n++){
        const int col = col0 + wc*64 + n*16 + lr;
        const float bcol = BIAS_ROW ? 0.f : bias[col];
        #pragma unroll
        for (int e=0;e<4;e++){
          size_t row = row0 + wr*64 + m*16 + lg*4 + e;
          float b = BIAS_ROW ? bias[row] : bcol;
          Cw[(m*16 + lg*4 + e)*72 + n*16 + lr] = f2bf_rn((acc[m][n][e] + b) * scale);
        }
      }
    }
    __syncthreads();
    u16* uo = reinterpret_cast<u16*>(Cout);
    #pragma unroll
    for (int i=0;i<8;i++){
      int rr = i*8 + (lane >> 3), cc = (lane & 7) * 8;
      bf16x8 v = *reinterpret_cast<const bf16x8*>(&Cw[rr*72 + cc]);
      *reinterpret_cast<bf16x8*>(&uo[(row0 + wr*64 + rr)*(size_t)ldc + col0 + wc*64 + cc]) = v;
    }
  }
}

// fused Q+K: Bt = wq||wk concat [1536][768]; 12 col tiles fastest. LDS-repack epilogue.
__global__ __launch_bounds__(256) void gemm_qk_kernel(
    const u16* __restrict__ A, const u16* __restrict__ Wqk,
    const float* __restrict__ bq, const float* __restrict__ bk,
    u16* __restrict__ Qb, u16* __restrict__ Kb)
{
  int g = xcd_remap(blockIdx.x, gridDim.x);
  int colt = g % 12, rowt = g / 12;
  const size_t row0 = (size_t)rowt * 128;
  const int col0 = colt * 128;
  GEMM_PROLOG
  GEMM_MAINLOOP(A, Wqk)

  const bool isk = col0 >= 768;
  const float scale = isk ? 1.f : QSCALE;
  u16* dst = isk ? Kb : Qb;
  const int ocol0 = isk ? col0 - 768 : col0;

  __syncthreads();
  u16* Cw = (wid < 2 ? As : Bs) + (wid & 1) * 4608;  // 64x72 u16
  #pragma unroll
  for (int m=0;m<4;m++){
    #pragma unroll
    for (int n=0;n<4;n++){
      const int ocol = ocol0 + wc*64 + n*16 + lr;
      const float b = isk ? bk[ocol] : bq[ocol];
      #pragma unroll
      for (int e=0;e<4;e++)
        Cw[(m*16 + lg*4 + e)*72 + n*16 + lr] = f2bf_rn((acc[m][n][e] + b) * scale);
    }
  }
  __syncthreads();
  #pragma unroll
  for (int i=0;i<8;i++){
    int rr = i*8 + (lane >> 3), cc = (lane & 7) * 8;
    size_t grow = row0 + wr*64 + rr;
    if (isk || grow < TOK){
      bf16x8 v = *reinterpret_cast<const bf16x8*>(&Cw[rr*72 + cc]);
      *reinterpret_cast<bf16x8*>(&dst[grow*D_MODEL + ocol0 + wc*64 + cc]) = v;
    }
  }
}

// ---------------- attention compute for one staged KV tile (R14/R12 structure) ----------------
template<int NK>
__device__ __forceinline__ void attn_compute(
    int lr, int lg,
    const u16 (* __restrict__ Ks)[72], const u16 (* __restrict__ Vs)[72],
    u16 (* __restrict__ Pw)[72],
    const bf16x8 (&qf)[2][2], float (&m_run)[2], float (&l_run)[2], f32x4 (&of)[2][4])
{
  constexpr int NCF = NK/16;
  constexpr int NKT = NK/32;

  f32x4 s2[2][NCF];
  #pragma unroll
  for (int c=0;c<NCF;c++){
    bf16x8 kf0 = *reinterpret_cast<const bf16x8*>(&Ks[c*16 + lr][lg*8]);
    bf16x8 kf1 = *reinterpret_cast<const bf16x8*>(&Ks[c*16 + lr][32 + lg*8]);
    #pragma unroll
    for (int r=0;r<2;r++){
      f32x4 s = f32x4{0.f,0.f,0.f,0.f};
      s = __builtin_amdgcn_mfma_f32_16x16x32_bf16(kf0, qf[r][0], s, 0,0,0);
      s = __builtin_amdgcn_mfma_f32_16x16x32_bf16(kf1, qf[r][1], s, 0,0,0);
      s2[r][c] = s;
    }
  }

  bf16x8 vf[NKT][4];
  #pragma unroll
  for (int kt=0;kt<NKT;kt++)
    #pragma unroll
    for (int c=0;c<4;c++)
      vf[kt][c] = *reinterpret_cast<const bf16x8*>(&Vs[c*16 + lr][kt*32 + lg*8]);

  #pragma unroll
  for (int r=0;r<2;r++){
    float tm = s2[r][0][0];
    #pragma unroll
    for (int c=0;c<NCF;c++)
      #pragma unroll
      for (int e=0;e<4;e++) tm = fmaxf(tm, s2[r][c][e]);
    tm = fmaxf(tm, __shfl_xor(tm, 16, 64));
    tm = fmaxf(tm, __shfl_xor(tm, 32, 64));
    if (!__all(tm - m_run[r] <= DEFER_THR)){
      float mnew = fmaxf(m_run[r], tm);
      float al = exp2f(m_run[r] - mnew);
      m_run[r] = mnew;
      l_run[r] *= al;
      #pragma unroll
      for (int c=0;c<4;c++)
        #pragma unroll
        for (int e=0;e<4;e++) of[r][c][e] *= al;
    }
    float ts = 0.f;
    #pragma unroll
    for (int c=0;c<NCF;c++)
      #pragma unroll
      for (int e=0;e<4;e++){
        float p = exp2f(s2[r][c][e] - m_run[r]);
        s2[r][c][e] = p;
        ts += p;
      }
    ts += __shfl_xor(ts, 16, 64);
    ts += __shfl_xor(ts, 32, 64);
    l_run[r] += ts;

    #pragma unroll
    for (int c=0;c<NCF;c++){
      ushort4 pk;
      pk.x = f2bf_rn(s2[r][c][0]); pk.y = f2bf_rn(s2[r][c][1]);
      pk.z = f2bf_rn(s2[r][c][2]); pk.w = f2bf_rn(s2[r][c][3]);
      *reinterpret_cast<ushort4*>(&Pw[lr][c*16 + lg*4]) = pk;
    }
    #pragma unroll
    for (int kt=0;kt<NKT;kt++){
      bf16x8 pf = *reinterpret_cast<const bf16x8*>(&Pw[lr][kt*32 + lg*8]);
      #pragma unroll
      for (int c=0;c<4;c++)
        of[r][c] = __builtin_amdgcn_mfma_f32_16x16x32_bf16(vf[kt][c], pf, of[r][c], 0,0,0);
    }
  }
}

// ---------------- attention: 512 thr / 8 waves, 256 q-rows per block ----------------
__global__ __launch_bounds__(512) void attn_kernel(
    const u16* __restrict__ Qb, const u16* __restrict__ Kb,
    const u16* __restrict__ Vt, u16* __restrict__ AO)
{
  __shared__ u16 Ks[64][72];
  __shared__ u16 Vs[64][72];
  __shared__ u16 PwAll[8][16][72];

  const int t = threadIdx.x;
  const int lane = t & 63, w = t >> 6;          // 8 waves
  const int lr = lane & 15, lg = lane >> 4;
  const int qh = blockIdx.x;                    // 0..1: 256-row half of the chunk
  const int h  = blockIdx.y;
  const int b  = blockIdx.z >> 4, ch = blockIdx.z & 15;
  const size_t tok0 = (size_t)b*SEQ + (size_t)ch*CHUNK_SZ + (size_t)qh*256;
  const size_t bch0 = (size_t)b*SEQ + (size_t)ch*CHUNK_SZ;
  u16 (* __restrict__ Pw)[72] = PwAll[w];

  bf16x8 qf[2][2];
  #pragma unroll
  for (int r=0;r<2;r++)
    #pragma unroll
    for (int kk=0;kk<2;kk++)
      qf[r][kk] = *reinterpret_cast<const bf16x8*>(
          &Qb[(tok0 + w*32 + r*16 + lr)*D_MODEL + (size_t)h*HEAD_DIM + kk*32 + lg*8]);

  float m_run[2] = {-INFINITY, -INFINITY};
  float l_run[2] = {0.f, 0.f};
  f32x4 of[2][4];
  #pragma unroll
  for (int r=0;r<2;r++)
    #pragma unroll
    for (int c=0;c<4;c++) of[r][c] = f32x4{0.f,0.f,0.f,0.f};

  // ---- landmark tile (32 keys), staged by waves 0-3 ----
  if (t < 256){
    const size_t lmrow0 = (size_t)TOK + (size_t)b*N_LM;
    int key = t >> 3, dc = (t & 7) << 3;
    *reinterpret_cast<bf16x8*>(&Ks[key][dc]) = *reinterpret_cast<const bf16x8*>(
        &Kb[(lmrow0 + key)*D_MODEL + (size_t)h*HEAD_DIM + dc]);
    int d = t >> 2, kc = (t & 3) << 3;
    *reinterpret_cast<bf16x8*>(&Vs[d][kc]) = *reinterpret_cast<const bf16x8*>(
        &Vt[((size_t)h*HEAD_DIM + d)*MKV_PAD + lmrow0 + kc]);
  }
  __syncthreads();
  attn_compute<32>(lr, lg, Ks, Vs, Pw, qf, m_run, l_run, of);

  // ---- 8 local tiles of 64 keys, reg-prefetched; 1 K + 1 V load per thread per tile ----
  bf16x8 kreg, vreg;
  const int key0 = t >> 3, dc0 = (t & 7) << 3;   // 512 thr: keys 0..63 x 8 col-chunks
  const int d0 = t >> 3, kc0 = (t & 7) << 3;
  {
    size_t col0 = bch0;
    kreg = *reinterpret_cast<const bf16x8*>(&Kb[(col0 + key0)*D_MODEL + (size_t)h*HEAD_DIM + dc0]);
    vreg = *reinterpret_cast<const bf16x8*>(&Vt[((size_t)h*HEAD_DIM + d0)*MKV_PAD + col0 + kc0]);
  }
  for (int tl = 0; tl < 8; ++tl){
    __syncthreads();
    *reinterpret_cast<bf16x8*>(&Ks[key0][dc0]) = kreg;
    *reinterpret_cast<bf16x8*>(&Vs[d0][kc0])   = vreg;
    __syncthreads();
    if (tl < 7){
      size_t col0 = bch0 + (size_t)(tl+1)*64;
      kreg = *reinterpret_cast<const bf16x8*>(&Kb[(col0 + key0)*D_MODEL + (size_t)h*HEAD_DIM + dc0]);
      vreg = *reinterpret_cast<const bf16x8*>(&Vt[((size_t)h*HEAD_DIM + d0)*MKV_PAD + col0 + kc0]);
    }
    attn_compute<64>(lr, lg, Ks, Vs, Pw, qf, m_run, l_run, of);
  }

  // ---- epilogue ----
  #pragma unroll
  for (int r=0;r<2;r++){
    float inv = 1.f / l_run[r];
    size_t row = (tok0 + w*32 + r*16 + lr)*D_MODEL + (size_t)h*HEAD_DIM;
    #pragma unroll
    for (int c=0;c<4;c++){
      ushort4 pk;
      pk.x = f2bf_rn(of[r][c][0]*inv); pk.y = f2bf_rn(of[r][c][1]*inv);
      pk.z = f2bf_rn(of[r][c][2]*inv); pk.w = f2bf_rn(of[r][c][3]*inv);
      *reinterpret_cast<ushort4*>(&AO[row + c*16 + lg*4]) = pk;
    }
  }
}

// ---------------- launch ----------------
extern "C" void kernel_launch(void* const* d_in, const int* in_sizes, int n_in,
                              void* d_out, int out_size, void* d_ws, size_t ws_size,
                              hipStream_t stream) {
  const float* x  = (const float*)d_in[0];
  const float* Wq = (const float*)d_in[1];
  const float* bq = (const float*)d_in[2];
  const float* Wk = (const float*)d_in[3];
  const float* bk = (const float*)d_in[4];
  const float* Wv = (const float*)d_in[5];
  const float* bv = (const float*)d_in[6];
  const float* Wo = (const float*)d_in[7];
  const float* bo = (const float*)d_in[8];
  float* out = (float*)d_out;

  // workspace layout (bytes)
  const size_t XCAT_OFF = 0;
  const size_t Q_OFF    = 25362432;
  const size_t K_OFF    = 50528256;
  const size_t VT_OFF   = 75890688;
  const size_t AO_OFF   = 101253120;
  const size_t WQ_OFF   = 126418944;
  const size_t WK_OFF   = 127598592;
  const size_t WV_OFF   = 128778240;
  const size_t WO_OFF   = 129957888;
  const size_t TOTAL    = 131137536;
  if (ws_size < TOTAL) return;

  char* ws = (char*)d_ws;
  u16* xcat = (u16*)(ws + XCAT_OFF);
  u16* Qb   = (u16*)(ws + Q_OFF);
  u16* Kb   = (u16*)(ws + K_OFF);
  u16* Vt   = (u16*)(ws + VT_OFF);
  u16* AO   = (u16*)(ws + AO_OFF);
  float* lmp = (float*)(ws + AO_OFF);
  u16* wqkb = (u16*)(ws + WQ_OFF);
  u16* wkb  = (u16*)(ws + WK_OFF);
  u16* wvb  = (u16*)(ws + WV_OFF);
  u16* wob  = (u16*)(ws + WO_OFF);

  dim3 blk(256);
  cvt4_kernel<<<dim3(2304), blk, 0, stream>>>(Wq, Wk, Wv, Wo, wqkb, wkb, wvb, wob);
  build_xcat_kernel<<<dim3(4096), blk, 0, stream>>>(x, xcat);
  lm_part_kernel<<<dim3(512), blk, 0, stream>>>(xcat, lmp);   // reads bf16 xcat (25MB, L2-warm)
  lm_final_kernel<<<dim3(64), blk, 0, stream>>>(lmp, xcat);

  // fused Q+K: 129 row tiles x 12 col tiles, col-fastest within XCD chunk
  gemm_qk_kernel<<<dim3(1548), blk, 0, stream>>>(xcat, wqkb, bq, bk, Qb, Kb);
  // V^T = Wv * xcat^T: 6 row tiles (wv) x 129 col tiles (tokens), row-fastest
  gemm_bt_kernel<0,1,1,6><<<dim3(774), blk, 0, stream>>>(wvb, xcat, bv, (void*)Vt, MKV_PAD, 1.f);

  attn_kernel<<<dim3(2, 12, 32), dim3(512), 0, stream>>>(Qb, Kb, Vt, AO);

  // out = AO * wo^T + bo: 128 row tiles x 6 col tiles, col-fastest
  gemm_bt_kernel<1,0,0,6><<<dim3(768), blk, 0, stream>>>(AO, wob, bo, (void*)out, D_MODEL, 1.f);
}